// Round 13
// baseline (534.764 us; speedup 1.0000x reference)
//
#include <hip/hip_runtime.h>
#include <hip/hip_bf16.h>
#include <stdint.h>

// Problem constants (fixed by setup_inputs)
#define Bn 64
#define Sn 2048
#define Dn 768
#define An 256
#define EPSF 1e-7f
#define ROWS 32              // s-rows per chunk
#define NCHUNK (Sn / ROWS)   // 64 chunks per batch
#define NK (Dn / 32)         // 24 K-steps of 32
#define CPB 16               // chunks per block
#define NBLK ((Bn * NCHUNK) / CPB)   // 256 blocks == 1 per CU

typedef __bf16 bf16x8 __attribute__((ext_vector_type(8)));
typedef float f32x4 __attribute__((ext_vector_type(4)));

__device__ __forceinline__ void g2lds16(const void* g, void* l) {
  __builtin_amdgcn_global_load_lds(
      (__attribute__((address_space(1))) void*)(g),
      (__attribute__((address_space(3))) void*)(l), 16, 0, 0);
}

// ---------------- pack W (fp32 row-major DxA) -> bf16 MFMA-B-fragment layout ----
__global__ void pack_w_kernel(const float* __restrict__ W, unsigned short* __restrict__ pw) {
  int kk = blockIdx.x >> 4;     // 0..23
  int cb = blockIdx.x & 15;     // 0..15
  int l  = threadIdx.x;         // 0..63
  int a  = cb * 16 + (l & 15);
  int k0 = kk * 32 + (l >> 4) * 8;
  bf16x8 pk;
#pragma unroll
  for (int j = 0; j < 8; ++j) pk[j] = (__bf16)W[(k0 + j) * An + a];
  *(bf16x8*)(pw + ((size_t)((kk * 16 + cb) * 64 + l)) * 8) = pk;
}

// ---------------- main: persistent blocks, zero-VGPR glds prefetch ----------------
// 256 blocks (1/CU), 512 threads = 8 waves. x stays fp32 in LDS (cvt in K-loop).
// Three 48KB half-chunk buffers rotate; next chunk's halves are staged by
// global_load_lds (no registers!) issued mid-iteration so HBM streams under
// the compute phases. Source-addr XOR swizzle + linear LDS dest (R7-proven).
// W B-frags: depth-4 register rotation (R10-proven). Raw barriers, lgkm-only
// drains; the single vmcnt(0) per iter IS the BW pacing (HBM busy while waiting).
__launch_bounds__(512, 2)
__global__ void attn_pool_main(const float* __restrict__ x,
                               const unsigned short* __restrict__ pw,
                               const float* __restrict__ bias,
                               const float* __restrict__ u,
                               const int* __restrict__ mask,
                               float* __restrict__ outpart,
                               float* __restrict__ sumpart) {
  __shared__ __align__(16) char hb[3][49152];   // 3 x (32 rows x 1536B fp32 half-rows)
  __shared__ float aitp[256];                   // [8 waves][32 rows]
  __shared__ float aitv[32];

  const int tid  = threadIdx.x;
  const int lane = tid & 63;
  const int wv   = tid >> 6;        // 0..7, owns cols wv*32..wv*32+31
  const int cid0 = blockIdx.x * CPB;
  const int b    = cid0 >> 6;       // constant per block
  const char* xb = (const char*)x + (size_t)b * Sn * 3072;

  const int arow  = lane & 15;
  const int khalf = lane >> 4;
  const int swz   = (arow & 7) << 4;      // rows r and r+16 share (r&7) -> same swz
  const char* wl  = (const char*)pw + (size_t)wv * 2048 + (size_t)lane * 16;

  // bias/u preloaded once (keeps the iter loop free of extra vmem waits)
  float bia[2], uvv[2];
#pragma unroll
  for (int cbi = 0; cbi < 2; ++cbi) {
    int col = wv * 32 + cbi * 16 + arow;
    bia[cbi] = bias[col];
    uvv[cbi] = u[col];
  }

  // ---- prologue: glds both halves of chunk 0 into hb[0], hb[1] ----
  {
    const int s0 = (cid0 & 63) * ROWS;
#pragma unroll
    for (int j = 0; j < 6; ++j) {
      int unit = tid + j * 512;          // 0..3071 granules (16B); 96 per half-row
      int row = unit / 96, g = unit % 96;
      const char* rb = xb + (size_t)(s0 + row) * 3072;
      int so = (g * 16) ^ ((row & 7) << 4);
      g2lds16(rb + so, (char*)hb[0] + unit * 16);
      g2lds16(rb + 1536 + so, (char*)hb[1] + unit * 16);
    }
  }

  for (int i = 0; i < CPB; ++i) {
    const int cid = cid0 + i;
    const int s0  = (cid & 63) * ROWS;
    const int hlo = (2 * i) % 3;
    const int hhi = (2 * i + 1) % 3;
    const int hnf = (2 * i + 2) % 3;    // next chunk's first half target
    const char* blo = (const char*)hb[hlo];
    const char* bhi = (const char*)hb[hhi];

    asm volatile("s_waitcnt vmcnt(0)" ::: "memory");   // halves landed (BW-paced)
    __builtin_amdgcn_sched_barrier(0);
    __builtin_amdgcn_s_barrier();

    float mval = 0.f;
    if (tid < 32) mval = (float)mask[(size_t)b * Sn + s0 + tid];

    // ---- wf prologue (depth-4 x 2 frags) ----
    bf16x8 wf[4][2];
#pragma unroll
    for (int s = 0; s < 4; ++s) {
      wf[s][0] = *(const bf16x8*)(wl + (size_t)s * 16384);
      wf[s][1] = *(const bf16x8*)(wl + (size_t)s * 16384 + 1024);
    }

    f32x4 acc[2][2];
#pragma unroll
    for (int p = 0; p < 2; ++p)
#pragma unroll
      for (int q = 0; q < 2; ++q) acc[p][q] = (f32x4){0.f, 0.f, 0.f, 0.f};

#define KSTEP(BUF, KK, KKL)                                                     \
    {                                                                           \
      const int s_ = (KK) & 3;                                                  \
      int base0 = arow * 1536 + (KKL) * 128 + khalf * 32;                       \
      int base1 = (arow + 16) * 1536 + (KKL) * 128 + khalf * 32;                \
      float4 q0a = *(const float4*)((BUF) + ((base0     ) ^ swz));              \
      float4 q0b = *(const float4*)((BUF) + ((base0 + 16) ^ swz));              \
      float4 q1a = *(const float4*)((BUF) + ((base1     ) ^ swz));              \
      float4 q1b = *(const float4*)((BUF) + ((base1 + 16) ^ swz));              \
      bf16x8 a0, a1;                                                            \
      a0[0] = (__bf16)q0a.x; a0[1] = (__bf16)q0a.y; a0[2] = (__bf16)q0a.z;      \
      a0[3] = (__bf16)q0a.w; a0[4] = (__bf16)q0b.x; a0[5] = (__bf16)q0b.y;      \
      a0[6] = (__bf16)q0b.z; a0[7] = (__bf16)q0b.w;                             \
      a1[0] = (__bf16)q1a.x; a1[1] = (__bf16)q1a.y; a1[2] = (__bf16)q1a.z;      \
      a1[3] = (__bf16)q1a.w; a1[4] = (__bf16)q1b.x; a1[5] = (__bf16)q1b.y;      \
      a1[6] = (__bf16)q1b.z; a1[7] = (__bf16)q1b.w;                             \
      bf16x8 b0 = wf[s_][0], b1 = wf[s_][1];                                    \
      if ((KK) + 4 < NK) {                                                      \
        wf[s_][0] = *(const bf16x8*)(wl + (size_t)((KK) + 4) * 16384);          \
        wf[s_][1] = *(const bf16x8*)(wl + (size_t)((KK) + 4) * 16384 + 1024);   \
      }                                                                         \
      acc[0][0] = __builtin_amdgcn_mfma_f32_16x16x32_bf16(a0, b0, acc[0][0], 0, 0, 0); \
      acc[1][0] = __builtin_amdgcn_mfma_f32_16x16x32_bf16(a1, b0, acc[1][0], 0, 0, 0); \
      acc[0][1] = __builtin_amdgcn_mfma_f32_16x16x32_bf16(a0, b1, acc[0][1], 0, 0, 0); \
      acc[1][1] = __builtin_amdgcn_mfma_f32_16x16x32_bf16(a1, b1, acc[1][1], 0, 0, 0); \
    }

#pragma unroll
    for (int kk = 0; kk < 12; ++kk) KSTEP(blo, kk, kk)
#pragma unroll
    for (int kk = 12; kk < 24; ++kk) KSTEP(bhi, kk, kk - 12)
#undef KSTEP

    __builtin_amdgcn_sched_barrier(0);
    // ---- issue next chunk's FIRST half -> hb[hnf] (streams under epi/pool) ----
    if (i + 1 < CPB) {
      const int ns0 = ((cid + 1) & 63) * ROWS;
#pragma unroll
      for (int j = 0; j < 6; ++j) {
        int unit = tid + j * 512;
        int row = unit / 96, g = unit % 96;
        g2lds16(xb + (size_t)(ns0 + row) * 3072 + ((g * 16) ^ ((row & 7) << 4)),
                (char*)hb[hnf] + unit * 16);
      }
      __builtin_amdgcn_sched_barrier(0);
    }

    // ---- epilogue: tanh + u-dot -> per-row partials ----
    float rowp[8];
#pragma unroll
    for (int p = 0; p < 8; ++p) rowp[p] = 0.f;
#pragma unroll
    for (int cbi = 0; cbi < 2; ++cbi) {
#pragma unroll
      for (int rb = 0; rb < 2; ++rb) {
#pragma unroll
        for (int r = 0; r < 4; ++r) {
          float v = acc[rb][cbi][r] + bia[cbi];
          v = fminf(fmaxf(v, -15.f), 15.f);
          float e2 = __expf(2.f * v);
          float th = (e2 - 1.f) * __builtin_amdgcn_rcpf(e2 + 1.f);
          rowp[rb * 4 + r] += th * uvv[cbi];
        }
      }
    }
#pragma unroll
    for (int m = 1; m < 16; m <<= 1)
#pragma unroll
      for (int p = 0; p < 8; ++p) rowp[p] += __shfl_xor(rowp[p], m, 64);

    if (arow == 0) {
#pragma unroll
      for (int rb = 0; rb < 2; ++rb)
#pragma unroll
        for (int r = 0; r < 4; ++r)
          aitp[wv * 32 + rb * 16 + khalf * 4 + r] = rowp[rb * 4 + r];
    }
    asm volatile("s_waitcnt lgkmcnt(0)" ::: "memory");
    __builtin_amdgcn_s_barrier();     // aitp ready (glds keep flying)

    if (tid < 32) {
      float s = 0.f;
#pragma unroll
      for (int k = 0; k < 8; ++k) s += aitp[k * 32 + tid];
      float av = __expf(s) * mval;
      aitv[tid] = av;
      float t = av;
#pragma unroll
      for (int m = 1; m < 32; m <<= 1) t += __shfl_xor(t, m, 64);
      if (tid == 0) sumpart[cid] = t;
    }
    asm volatile("s_waitcnt lgkmcnt(0)" ::: "memory");
    __builtin_amdgcn_s_barrier();     // aitv ready

    // ---- pooling: 96 threads x 8-d units, rotated row order (fewer conflicts) ----
    float pac[8];
#pragma unroll
    for (int e = 0; e < 8; ++e) pac[e] = 0.f;
    const int du = tid;
    if (tid < 96) {
      const char* pb = (du < 48) ? blo : bhi;
      const int dl = (du < 48) ? du : du - 48;
#pragma unroll
      for (int rr = 0; rr < 32; ++rr) {
        int row = (rr + du) & 31;
        int sw  = (row & 7) << 4;
        int bse = row * 1536 + dl * 32;
        float4 v0 = *(const float4*)(pb + ((bse     ) ^ sw));
        float4 v1 = *(const float4*)(pb + ((bse + 16) ^ sw));
        float a = aitv[row];
        pac[0] += a * v0.x; pac[1] += a * v0.y; pac[2] += a * v0.z; pac[3] += a * v0.w;
        pac[4] += a * v1.x; pac[5] += a * v1.y; pac[6] += a * v1.z; pac[7] += a * v1.w;
      }
    }
    asm volatile("s_waitcnt lgkmcnt(0)" ::: "memory");
    __builtin_amdgcn_s_barrier();     // pool reads done -> hb[hlo] free

    // ---- issue next chunk's SECOND half -> hb[hlo] ----
    if (i + 1 < CPB) {
      const int ns0 = ((cid + 1) & 63) * ROWS;
#pragma unroll
      for (int j = 0; j < 6; ++j) {
        int unit = tid + j * 512;
        int row = unit / 96, g = unit % 96;
        g2lds16(xb + (size_t)(ns0 + row) * 3072 + 1536 + ((g * 16) ^ ((row & 7) << 4)),
                (char*)hb[hlo] + unit * 16);
      }
      __builtin_amdgcn_sched_barrier(0);
    }

    if (tid < 96) {
      float* op = outpart + (size_t)cid * Dn + du * 8;
#pragma unroll
      for (int e = 0; e < 8; ++e) op[e] = pac[e];
    }
  }
}

// ---------------- finalize: out[b,d] = sum_c outpart / (sum_c sumpart + eps) ----
// grid = 64 b x 3 slabs of 256 d
__global__ void finalize_kernel(const float* __restrict__ outpart,
                                const float* __restrict__ sumpart,
                                float* __restrict__ out) {
  __shared__ float sh;
  int b = blockIdx.x / 3, slab = blockIdx.x % 3;
  int tid = threadIdx.x;
  if (tid < 64) {
    float v = sumpart[b * 64 + tid];
#pragma unroll
    for (int m = 1; m < 64; m <<= 1) v += __shfl_xor(v, m, 64);
    if (tid == 0) sh = v + EPSF;
  }
  __syncthreads();
  float inv = 1.0f / sh;
  int d = slab * 256 + tid;
  const float* p = outpart + (size_t)b * 64 * Dn + d;
  float s = 0.f;
#pragma unroll 8
  for (int c = 0; c < 64; ++c) s += p[(size_t)c * Dn];
  out[b * Dn + d] = s * inv;
}

extern "C" void kernel_launch(void* const* d_in, const int* in_sizes, int n_in,
                              void* d_out, int out_size, void* d_ws, size_t ws_size,
                              hipStream_t stream) {
  const float* x    = (const float*)d_in[0];
  const float* W    = (const float*)d_in[1];
  const float* bias = (const float*)d_in[2];
  const float* u    = (const float*)d_in[3];
  const int*   mask = (const int*)d_in[4];
  float* out = (float*)d_out;

  unsigned short* pw = (unsigned short*)d_ws;                      // 393216 B
  float* outpart = (float*)((char*)d_ws + 393216);                 // 64*64*768*4 = 12.58 MB
  float* sumpart = (float*)((char*)d_ws + 393216 + 12582912);      // 16 KB

  hipLaunchKernelGGL(pack_w_kernel, dim3(24 * 16), dim3(64), 0, stream, W, pw);
  hipLaunchKernelGGL(attn_pool_main, dim3(NBLK), dim3(512), 0, stream,
                     x, pw, bias, u, mask, outpart, sumpart);
  hipLaunchKernelGGL(finalize_kernel, dim3(Bn * 3), dim3(256), 0, stream,
                     outpart, sumpart, out);
}

// Round 14
// 154.373 us; speedup vs baseline: 3.4641x; 3.4641x over previous
//
#include <hip/hip_runtime.h>
#include <hip/hip_bf16.h>
#include <stdint.h>

// Problem constants (fixed by setup_inputs)
#define Bn 64
#define Sn 2048
#define Dn 768
#define An 256
#define EPSF 1e-7f
#define ROWS 64              // s-rows per block (2 chunks of 32)
#define NBLK ((Bn * Sn) / ROWS)   // 2048 blocks, 1 per CU resident, 8 rounds
#define NK (Dn / 32)         // 24 K-steps of 32

typedef __bf16 bf16x8 __attribute__((ext_vector_type(8)));
typedef float f32x4 __attribute__((ext_vector_type(4)));

// ---------------- pack W (fp32 row-major DxA) -> bf16 MFMA-B-fragment layout ----
// packed[( (kk*16 + cb)*64 + lane )*8 + e] = bf16( W[kk*32 + (lane>>4)*8 + e][cb*16 + (lane&15)] )
__global__ void pack_w_kernel(const float* __restrict__ W, unsigned short* __restrict__ pw) {
  int kk = blockIdx.x >> 4;     // 0..23
  int cb = blockIdx.x & 15;     // 0..15
  int l  = threadIdx.x;         // 0..63
  int a  = cb * 16 + (l & 15);
  int k0 = kk * 32 + (l >> 4) * 8;
  bf16x8 pk;
#pragma unroll
  for (int j = 0; j < 8; ++j) pk[j] = (__bf16)W[(k0 + j) * An + a];
  *(bf16x8*)(pw + ((size_t)((kk * 16 + cb) * 64 + l)) * 8) = pk;
}

// ---------------- main fused kernel: 64-row tiles (halved W L2 traffic) ----------------
// 2048 one-shot blocks, 512 threads = 8 waves, 1 block/CU (LDS ~110KB).
// Staging: R11-proven batch-issue (24 float4/thread, sched_barrier-pinned),
// fp32 -> bf16 -> XOR-swizzled LDS. K-loop: wf depth-4 rotation (R10-proven),
// 8 waves x 2 col-frags x 4 row-frags. Per W fetch (384KB L2) we now compute
// 64 rows instead of 32 -> W L2 stream halves (1.57GB -> 786MB) and hides
// under MFMA instead of serializing after the stage phase.
__launch_bounds__(512, 2)
__global__ void attn_pool_main(const float* __restrict__ x,
                               const unsigned short* __restrict__ pw,
                               const float* __restrict__ bias,
                               const float* __restrict__ u,
                               const int* __restrict__ mask,
                               float* __restrict__ outpart,
                               float* __restrict__ sumpart) {
  __shared__ __align__(16) char xs[98304];   // 64 rows x 768 bf16, XOR-swizzled
  __shared__ float aitp[512];                // [8 waves][64 rows]
  __shared__ float aitv[64];
  __shared__ float outred[3072];             // [4 row-groups][768]

  const int tid  = threadIdx.x;
  const int lane = tid & 63;
  const int wv   = tid >> 6;          // wave 0..7, owns cols wv*32..wv*32+31
  const int bid  = blockIdx.x;
  const int b    = bid >> 5;          // 32 blocks per batch
  const int s0   = (bid & 31) * ROWS;
  const int cid0 = (bid << 1);        // 32-row chunk ids (for sumpart/outpart)

  float mval = 0.f;
  if (tid < 64) mval = (float)mask[(size_t)b * Sn + s0 + tid];

  // ---- stage x tile: 64 rows x 768 fp32 -> bf16 LDS (swizzled) ----
  const float* xb = x + ((size_t)b * Sn + s0) * Dn;
  {
    float4 ldA[12], ldB[12];
#pragma unroll
    for (int j = 0; j < 12; ++j) {
      int unit = tid + j * 512;       // 0..6143 ; 8 k-elems each
      int row  = unit / 96;
      int ku   = unit % 96;
      const float4* g = (const float4*)(xb + (size_t)row * Dn + ku * 8);
      ldA[j] = g[0];
      ldB[j] = g[1];
    }
    __builtin_amdgcn_sched_barrier(0);   // keep all 24 loads issued up-front
#pragma unroll
    for (int j = 0; j < 12; ++j) {
      int unit = tid + j * 512;
      int row  = unit / 96;
      int ku   = unit % 96;
      bf16x8 pk;
      pk[0] = (__bf16)ldA[j].x; pk[1] = (__bf16)ldA[j].y;
      pk[2] = (__bf16)ldA[j].z; pk[3] = (__bf16)ldA[j].w;
      pk[4] = (__bf16)ldB[j].x; pk[5] = (__bf16)ldB[j].y;
      pk[6] = (__bf16)ldB[j].z; pk[7] = (__bf16)ldB[j].w;
      int off = (row * 1536 + ku * 16) ^ ((row & 7) << 4);
      *(bf16x8*)(xs + off) = pk;
    }
  }

  const int arow  = lane & 15;
  const int khalf = lane >> 4;
  const int kh16  = khalf * 16;
  const int swz   = (arow & 7) << 4;   // rows arow+16*rb share (arow&7)
  const char* wl  = (const char*)pw + (size_t)(wv * 2) * 1024 + (size_t)lane * 16;

  // ---- W pipeline prologue: kk=0..3 (ld regs dead now) ----
  bf16x8 wf[4][2];
#pragma unroll
  for (int s = 0; s < 4; ++s) {
    wf[s][0] = *(const bf16x8*)(wl + (size_t)s * 16384);
    wf[s][1] = *(const bf16x8*)(wl + (size_t)s * 16384 + 1024);
  }

  asm volatile("s_waitcnt lgkmcnt(0)" ::: "memory");
  __builtin_amdgcn_s_barrier();       // xs published; wf stream in flight

  f32x4 acc[4][2];
#pragma unroll
  for (int p = 0; p < 4; ++p)
#pragma unroll
    for (int q = 0; q < 2; ++q) acc[p][q] = (f32x4){0.f, 0.f, 0.f, 0.f};

  // ---- K-loop: use wf[kk&3], reload it for kk+4 (counted vmcnt waits) ----
#pragma unroll
  for (int kk = 0; kk < NK; ++kk) {
    const int s = kk & 3;
    bf16x8 a0 = *(const bf16x8*)(xs + (((arow     ) * 1536 + kk * 64 + kh16) ^ swz));
    bf16x8 a1 = *(const bf16x8*)(xs + (((arow + 16) * 1536 + kk * 64 + kh16) ^ swz));
    bf16x8 a2 = *(const bf16x8*)(xs + (((arow + 32) * 1536 + kk * 64 + kh16) ^ swz));
    bf16x8 a3 = *(const bf16x8*)(xs + (((arow + 48) * 1536 + kk * 64 + kh16) ^ swz));
    bf16x8 b0 = wf[s][0], b1 = wf[s][1];
    if (kk + 4 < NK) {
      const char* wk = wl + (size_t)(kk + 4) * 16384;
      wf[s][0] = *(const bf16x8*)(wk);
      wf[s][1] = *(const bf16x8*)(wk + 1024);
    }
    acc[0][0] = __builtin_amdgcn_mfma_f32_16x16x32_bf16(a0, b0, acc[0][0], 0, 0, 0);
    acc[1][0] = __builtin_amdgcn_mfma_f32_16x16x32_bf16(a1, b0, acc[1][0], 0, 0, 0);
    acc[2][0] = __builtin_amdgcn_mfma_f32_16x16x32_bf16(a2, b0, acc[2][0], 0, 0, 0);
    acc[3][0] = __builtin_amdgcn_mfma_f32_16x16x32_bf16(a3, b0, acc[3][0], 0, 0, 0);
    acc[0][1] = __builtin_amdgcn_mfma_f32_16x16x32_bf16(a0, b1, acc[0][1], 0, 0, 0);
    acc[1][1] = __builtin_amdgcn_mfma_f32_16x16x32_bf16(a1, b1, acc[1][1], 0, 0, 0);
    acc[2][1] = __builtin_amdgcn_mfma_f32_16x16x32_bf16(a2, b1, acc[2][1], 0, 0, 0);
    acc[3][1] = __builtin_amdgcn_mfma_f32_16x16x32_bf16(a3, b1, acc[3][1], 0, 0, 0);
  }

  // ---- epilogue: tanh + dot with u -> per-row partials (16 rows' worth) ----
  float rowp[16];
#pragma unroll
  for (int p = 0; p < 16; ++p) rowp[p] = 0.f;
#pragma unroll
  for (int cbi = 0; cbi < 2; ++cbi) {
    int col = wv * 32 + cbi * 16 + arow;
    float bia = bias[col];
    float uv  = u[col];
#pragma unroll
    for (int rb = 0; rb < 4; ++rb) {
#pragma unroll
      for (int r = 0; r < 4; ++r) {
        float v = acc[rb][cbi][r] + bia;
        v = fminf(fmaxf(v, -15.f), 15.f);
        float e2 = __expf(2.f * v);
        float th = (e2 - 1.f) * __builtin_amdgcn_rcpf(e2 + 1.f);
        rowp[rb * 4 + r] += th * uv;
      }
    }
  }
#pragma unroll
  for (int m = 1; m < 16; m <<= 1)
#pragma unroll
    for (int p = 0; p < 16; ++p) rowp[p] += __shfl_xor(rowp[p], m, 64);

  if (arow == 0) {
#pragma unroll
    for (int rb = 0; rb < 4; ++rb)
#pragma unroll
      for (int r = 0; r < 4; ++r)
        aitp[wv * 64 + rb * 16 + khalf * 4 + r] = rowp[rb * 4 + r];
  }
  asm volatile("s_waitcnt lgkmcnt(0)" ::: "memory");
  __builtin_amdgcn_s_barrier();       // aitp ready

  // ---- ait = exp(sum)*mask ; per-32-row-chunk sums ----
  if (tid < 64) {
    float s = 0.f;
#pragma unroll
    for (int k = 0; k < 8; ++k) s += aitp[k * 64 + tid];
    float av = __expf(s) * mval;
    aitv[tid] = av;
    float t = av;
#pragma unroll
    for (int m = 1; m < 32; m <<= 1) t += __shfl_xor(t, m, 64);  // 32-lane groups
    if (tid == 0)  sumpart[cid0]     = t;
    if (tid == 32) sumpart[cid0 + 1] = t;
  }
  asm volatile("s_waitcnt lgkmcnt(0)" ::: "memory");
  __builtin_amdgcn_s_barrier();       // aitv ready

  // ---- pooling: 384 threads, 4 row-groups of 16 rows ----
  {
    float pac[8];
#pragma unroll
    for (int e = 0; e < 8; ++e) pac[e] = 0.f;
    int rg = tid / 96;                // 0..3 for tid<384
    int du = tid % 96;                // 8-d unit
    if (tid < 384) {
#pragma unroll
      for (int rr = 0; rr < 16; ++rr) {
        int row = rg * 16 + rr;
        int off = (row * 1536 + du * 16) ^ ((row & 7) << 4);
        bf16x8 xv = *(const bf16x8*)(xs + off);
        float a = aitv[row];
#pragma unroll
        for (int e = 0; e < 8; ++e) pac[e] += a * (float)xv[e];
      }
#pragma unroll
      for (int e = 0; e < 8; ++e) outred[rg * 768 + du * 8 + e] = pac[e];
    }
  }
  asm volatile("s_waitcnt lgkmcnt(0)" ::: "memory");
  __builtin_amdgcn_s_barrier();       // outred ready

  // ---- write 2 chunk partials: rows 0-31 -> cid0, rows 32-63 -> cid0+1 ----
#pragma unroll
  for (int j = 0; j < 3; ++j) {
    int idx = tid + j * 512;          // 0..1535
    int c   = idx / 768;
    int d   = idx % 768;
    outpart[(size_t)(cid0 + c) * Dn + d] =
        outred[c * 1536 + d] + outred[c * 1536 + 768 + d];
  }
}

// ---------------- finalize: out[b,d] = sum_c outpart / (sum_c sumpart + eps) ----
// grid = 64 b x 3 slabs of 256 d
__global__ void finalize_kernel(const float* __restrict__ outpart,
                                const float* __restrict__ sumpart,
                                float* __restrict__ out) {
  __shared__ float sh;
  int b = blockIdx.x / 3, slab = blockIdx.x % 3;
  int tid = threadIdx.x;
  if (tid < 64) {
    float v = sumpart[b * 64 + tid];
#pragma unroll
    for (int m = 1; m < 64; m <<= 1) v += __shfl_xor(v, m, 64);
    if (tid == 0) sh = v + EPSF;
  }
  __syncthreads();
  float inv = 1.0f / sh;
  int d = slab * 256 + tid;
  const float* p = outpart + (size_t)b * 64 * Dn + d;
  float s = 0.f;
#pragma unroll 8
  for (int c = 0; c < 64; ++c) s += p[(size_t)c * Dn];
  out[b * Dn + d] = s * inv;
}

extern "C" void kernel_launch(void* const* d_in, const int* in_sizes, int n_in,
                              void* d_out, int out_size, void* d_ws, size_t ws_size,
                              hipStream_t stream) {
  const float* x    = (const float*)d_in[0];
  const float* W    = (const float*)d_in[1];
  const float* bias = (const float*)d_in[2];
  const float* u    = (const float*)d_in[3];
  const int*   mask = (const int*)d_in[4];
  float* out = (float*)d_out;

  unsigned short* pw = (unsigned short*)d_ws;                      // 393216 B
  float* outpart = (float*)((char*)d_ws + 393216);                 // 64*64*768*4 = 12.58 MB
  float* sumpart = (float*)((char*)d_ws + 393216 + 12582912);      // 16 KB

  hipLaunchKernelGGL(pack_w_kernel, dim3(24 * 16), dim3(64), 0, stream, W, pw);
  hipLaunchKernelGGL(attn_pool_main, dim3(NBLK), dim3(512), 0, stream,
                     x, pw, bias, u, mask, outpart, sumpart);
  hipLaunchKernelGGL(finalize_kernel, dim3(Bn * 3), dim3(256), 0, stream,
                     outpart, sumpart, out);
}

// Round 15
// 92.030 us; speedup vs baseline: 5.8107x; 1.6774x over previous
//
#include <hip/hip_runtime.h>
#include <hip/hip_bf16.h>
#include <stdint.h>

// Problem constants (fixed by setup_inputs)
#define Bn 64
#define Sn 2048
#define Dn 768
#define An 256
#define EPSF 1e-7f
#define ROWS 32              // s-rows per chunk
#define NK (Dn / 32)         // 24 K-steps of 32

typedef __bf16 bf16x8 __attribute__((ext_vector_type(8)));
typedef float f32x4 __attribute__((ext_vector_type(4)));

// ---------------- pack W (fp32 row-major DxA) -> bf16 MFMA-B-fragment layout ----
// packed[( (kk*16 + cb)*64 + lane )*8 + e] = bf16( W[kk*32 + (lane>>4)*8 + e][cb*16 + (lane&15)] )
__global__ void pack_w_kernel(const float* __restrict__ W, unsigned short* __restrict__ pw) {
  int kk = blockIdx.x >> 4;     // 0..23
  int cb = blockIdx.x & 15;     // 0..15
  int l  = threadIdx.x;         // 0..63
  int a  = cb * 16 + (l & 15);
  int k0 = kk * 32 + (l >> 4) * 8;
  bf16x8 pk;
#pragma unroll
  for (int j = 0; j < 8; ++j) pk[j] = (__bf16)W[(k0 + j) * An + a];
  *(bf16x8*)(pw + ((size_t)((kk * 16 + cb) * 64 + l)) * 8) = pk;
}

// ---------------- compact: per batch, indices of rows with mask==1 ----------------
// 64 blocks (1/batch), 256 threads; deterministic LDS prefix scan.
__global__ void compact_kernel(const int* __restrict__ mask,
                               int* __restrict__ ridx, int* __restrict__ count) {
  __shared__ int scan[256];
  const int b = blockIdx.x, t = threadIdx.x;
  const int* mrow = mask + (size_t)b * Sn;
  int loc[8], lc = 0;
#pragma unroll
  for (int k = 0; k < 8; ++k) {
    loc[k] = mrow[t * 8 + k];
    lc += loc[k];
  }
  scan[t] = lc;
  __syncthreads();
  for (int off = 1; off < 256; off <<= 1) {
    int v = scan[t];
    int add = (t >= off) ? scan[t - off] : 0;
    __syncthreads();
    scan[t] = v + add;
    __syncthreads();
  }
  int o = scan[t] - lc;               // exclusive prefix
  int* rb = ridx + (size_t)b * Sn;
#pragma unroll
  for (int k = 0; k < 8; ++k)
    if (loc[k]) rb[o++] = t * 8 + k;
  if (t == 255) count[b] = scan[255];
}

// ---------------- main fused kernel (R11 structure, active rows only) ----------------
// grid = 4096 slots; slot (b, ci) processes active rows [ci*32, ci*32+32) of
// batch b via the compacted index list; slots past count[b] exit immediately
// (~2048 do real work -> x HBM traffic halves to ~202MB, W L2 to ~786MB).
// Staging: batch-issued 24 float4/thread (R11-proven) through the row gather.
// K-loop: wf[4][4] depth-4 W register rotation (R10-proven).
__launch_bounds__(256, 3)
__global__ void attn_pool_main(const float* __restrict__ x,
                               const unsigned short* __restrict__ pw,
                               const float* __restrict__ bias,
                               const float* __restrict__ u,
                               const int* __restrict__ ridx,
                               const int* __restrict__ count,
                               float* __restrict__ outpart,
                               float* __restrict__ sumpart) {
  __shared__ __align__(16) char xs[49152];   // 32 rows x 768 bf16, XOR-swizzled
  __shared__ float aitp[128];
  __shared__ float aitv[32];
  __shared__ int rows[32];

  const int tid  = threadIdx.x;
  const int lane = tid & 63;
  const int w    = tid >> 6;      // wave 0..3, cols w*64..w*64+63
  const int cid  = blockIdx.x;
  const int b    = cid >> 6;
  const int ci   = cid & 63;
  const int base = ci * ROWS;
  const int ntot = count[b];
  if (base >= ntot) return;                    // inactive slot
  const int nact = min(ROWS, ntot - base);

  if (tid < 32)
    rows[tid] = ridx[(size_t)b * Sn + base + ((tid < nact) ? tid : 0)];
  __syncthreads();

  // ---- stage x tile: 32 gathered rows x 768 fp32 -> bf16 LDS (swizzled) ----
  const float* xbb = x + (size_t)b * Sn * Dn;
  {
    float4 ldA[12], ldB[12];
#pragma unroll
    for (int j = 0; j < 12; ++j) {
      int unit = tid + j * 256;       // 0..3071 ; 8 k-elems each
      int row  = unit / 96;
      int ku   = unit % 96;
      const float4* g = (const float4*)(xbb + (size_t)rows[row] * Dn + ku * 8);
      ldA[j] = g[0];
      ldB[j] = g[1];
    }
    __builtin_amdgcn_sched_barrier(0);   // keep all 24 loads issued up-front
#pragma unroll
    for (int j = 0; j < 12; ++j) {
      int unit = tid + j * 256;
      int row  = unit / 96;
      int ku   = unit % 96;
      bf16x8 pk;
      pk[0] = (__bf16)ldA[j].x; pk[1] = (__bf16)ldA[j].y;
      pk[2] = (__bf16)ldA[j].z; pk[3] = (__bf16)ldA[j].w;
      pk[4] = (__bf16)ldB[j].x; pk[5] = (__bf16)ldB[j].y;
      pk[6] = (__bf16)ldB[j].z; pk[7] = (__bf16)ldB[j].w;
      int off = (row * 1536 + ku * 16) ^ ((row & 7) << 4);
      *(bf16x8*)(xs + off) = pk;
    }
  }

  const int arow  = lane & 15;
  const int kh16  = (lane >> 4) * 16;
  const int swz   = (arow & 7) << 4;
  const char* wlane = (const char*)pw + (size_t)(w * 4) * 1024 + (size_t)lane * 16;

  // ---- W pipeline prologue: load kk=0..3 into wf (ld regs dead now) ----
  bf16x8 wf[4][4];
#pragma unroll
  for (int s = 0; s < 4; ++s) {
    const char* wk = wlane + (size_t)s * 16384;
    wf[s][0] = *(const bf16x8*)(wk);
    wf[s][1] = *(const bf16x8*)(wk + 1024);
    wf[s][2] = *(const bf16x8*)(wk + 2048);
    wf[s][3] = *(const bf16x8*)(wk + 3072);
  }

  asm volatile("s_waitcnt lgkmcnt(0)" ::: "memory");
  __builtin_amdgcn_s_barrier();     // xs published; wf stream in flight

  f32x4 acc[2][4];
#pragma unroll
  for (int p = 0; p < 2; ++p)
#pragma unroll
    for (int q = 0; q < 4; ++q) acc[p][q] = (f32x4){0.f, 0.f, 0.f, 0.f};

  // ---- K-loop: use wf[kk&3], reload it for kk+4 (counted vmcnt waits) ----
#pragma unroll
  for (int kk = 0; kk < NK; ++kk) {
    const int s = kk & 3;
    bf16x8 a0 = *(const bf16x8*)(xs + ((arow * 1536 + kk * 64 + kh16) ^ swz));
    bf16x8 a1 = *(const bf16x8*)(xs + (((arow + 16) * 1536 + kk * 64 + kh16) ^ swz));
    bf16x8 b0 = wf[s][0], b1 = wf[s][1], b2 = wf[s][2], b3 = wf[s][3];
    if (kk + 4 < NK) {
      const char* wk = wlane + (size_t)(kk + 4) * 16384;
      wf[s][0] = *(const bf16x8*)(wk);
      wf[s][1] = *(const bf16x8*)(wk + 1024);
      wf[s][2] = *(const bf16x8*)(wk + 2048);
      wf[s][3] = *(const bf16x8*)(wk + 3072);
    }
    acc[0][0] = __builtin_amdgcn_mfma_f32_16x16x32_bf16(a0, b0, acc[0][0], 0, 0, 0);
    acc[1][0] = __builtin_amdgcn_mfma_f32_16x16x32_bf16(a1, b0, acc[1][0], 0, 0, 0);
    acc[0][1] = __builtin_amdgcn_mfma_f32_16x16x32_bf16(a0, b1, acc[0][1], 0, 0, 0);
    acc[1][1] = __builtin_amdgcn_mfma_f32_16x16x32_bf16(a1, b1, acc[1][1], 0, 0, 0);
    acc[0][2] = __builtin_amdgcn_mfma_f32_16x16x32_bf16(a0, b2, acc[0][2], 0, 0, 0);
    acc[1][2] = __builtin_amdgcn_mfma_f32_16x16x32_bf16(a1, b2, acc[1][2], 0, 0, 0);
    acc[0][3] = __builtin_amdgcn_mfma_f32_16x16x32_bf16(a0, b3, acc[0][3], 0, 0, 0);
    acc[1][3] = __builtin_amdgcn_mfma_f32_16x16x32_bf16(a1, b3, acc[1][3], 0, 0, 0);
  }

  // ---- epilogue: tanh + dot with u -> per-row partials ----
  float rowp[8];
#pragma unroll
  for (int p = 0; p < 8; ++p) rowp[p] = 0.f;
#pragma unroll
  for (int cbi = 0; cbi < 4; ++cbi) {
    int col = w * 64 + cbi * 16 + arow;
    float bia = bias[col];
    float uv  = u[col];
#pragma unroll
    for (int rb = 0; rb < 2; ++rb) {
#pragma unroll
      for (int r = 0; r < 4; ++r) {
        float v = acc[rb][cbi][r] + bia;
        v = fminf(fmaxf(v, -15.f), 15.f);
        float e2 = __expf(2.f * v);
        float th = (e2 - 1.f) * __builtin_amdgcn_rcpf(e2 + 1.f);
        rowp[rb * 4 + r] += th * uv;
      }
    }
  }
#pragma unroll
  for (int m = 1; m < 16; m <<= 1)
#pragma unroll
    for (int p = 0; p < 8; ++p) rowp[p] += __shfl_xor(rowp[p], m, 64);

  if (arow == 0) {
    int rbase = (lane >> 4) * 4;
#pragma unroll
    for (int rb = 0; rb < 2; ++rb)
#pragma unroll
      for (int r = 0; r < 4; ++r)
        aitp[w * 32 + rb * 16 + rbase + r] = rowp[rb * 4 + r];
  }
  __syncthreads();

  // ---- ait = exp(sum) for active rows, 0 for pad ; chunk sum ----
  if (tid < 32) {
    float s = aitp[tid] + aitp[32 + tid] + aitp[64 + tid] + aitp[96 + tid];
    float av = (tid < nact) ? __expf(s) : 0.f;
    aitv[tid] = av;
    float t = av;
#pragma unroll
    for (int m = 1; m < 32; m <<= 1) t += __shfl_xor(t, m, 64);
    if (tid == 0) sumpart[cid] = t;
  }
  __syncthreads();

  // ---- pooling: 192 threads, 2 row-groups of 16 rows ----
  float pac[8];
#pragma unroll
  for (int e = 0; e < 8; ++e) pac[e] = 0.f;
  int rg = tid / 96;              // 0..1 for tid<192
  int du = tid % 96;              // 8-d unit
  if (tid < 192) {
#pragma unroll
    for (int rr = 0; rr < 16; ++rr) {
      int row = rg * 16 + rr;
      int off = (row * 1536 + du * 16) ^ ((row & 7) << 4);
      bf16x8 xv = *(const bf16x8*)(xs + off);
      float a = aitv[row];
#pragma unroll
      for (int e = 0; e < 8; ++e) pac[e] += a * (float)xv[e];
    }
  }
  __syncthreads();   // all xs reads done -> safe to overlay outred onto xs

  float* outred = (float*)xs;     // [2][768] overlay
  if (tid < 192) {
#pragma unroll
    for (int e = 0; e < 8; ++e) outred[rg * 768 + du * 8 + e] = pac[e];
  }
  __syncthreads();

  {
    float* op = outpart + (size_t)cid * Dn;
#pragma unroll
    for (int j = 0; j < 3; ++j) {
      int d = tid + j * 256;
      op[d] = outred[d] + outred[768 + d];
    }
  }
}

// ---------------- finalize: out[b,d] = sum over written chunks / (sum + eps) ----
// grid = 64 b x 3 slabs of 256 d; reads only the ceil(count/32) written slots.
__global__ void finalize_kernel(const float* __restrict__ outpart,
                                const float* __restrict__ sumpart,
                                const int* __restrict__ count,
                                float* __restrict__ out) {
  __shared__ float sh;
  int b = blockIdx.x / 3, slab = blockIdx.x % 3;
  int tid = threadIdx.x;
  const int nch = (count[b] + ROWS - 1) / ROWS;   // written chunk slots
  if (tid < 64) {
    float v = (tid < nch) ? sumpart[b * 64 + tid] : 0.f;
#pragma unroll
    for (int m = 1; m < 64; m <<= 1) v += __shfl_xor(v, m, 64);
    if (tid == 0) sh = v + EPSF;
  }
  __syncthreads();
  float inv = 1.0f / sh;
  int d = slab * 256 + tid;
  const float* p = outpart + (size_t)b * 64 * Dn + d;
  float s = 0.f;
  for (int c = 0; c < nch; ++c) s += p[(size_t)c * Dn];
  out[b * Dn + d] = s * inv;
}

extern "C" void kernel_launch(void* const* d_in, const int* in_sizes, int n_in,
                              void* d_out, int out_size, void* d_ws, size_t ws_size,
                              hipStream_t stream) {
  const float* x    = (const float*)d_in[0];
  const float* W    = (const float*)d_in[1];
  const float* bias = (const float*)d_in[2];
  const float* u    = (const float*)d_in[3];
  const int*   mask = (const int*)d_in[4];
  float* out = (float*)d_out;

  unsigned short* pw = (unsigned short*)d_ws;                       // 384 KB
  float* outpart = (float*)((char*)d_ws + 393216);                  // 12.58 MB
  float* sumpart = (float*)((char*)d_ws + 393216 + 12582912);       // 16 KB
  int*   ridx    = (int*)((char*)d_ws + 393216 + 12582912 + 16384); // 512 KB
  int*   count   = (int*)((char*)d_ws + 393216 + 12582912 + 16384 + 524288); // 256 B

  hipLaunchKernelGGL(pack_w_kernel, dim3(24 * 16), dim3(64), 0, stream, W, pw);
  hipLaunchKernelGGL(compact_kernel, dim3(Bn), dim3(256), 0, stream, mask, ridx, count);
  hipLaunchKernelGGL(attn_pool_main, dim3(Bn * 64), dim3(256), 0, stream,
                     x, pw, bias, u, ridx, count, outpart, sumpart);
  hipLaunchKernelGGL(finalize_kernel, dim3(Bn * 3), dim3(256), 0, stream,
                     outpart, sumpart, count, out);
}

// Round 16
// 89.130 us; speedup vs baseline: 5.9998x; 1.0325x over previous
//
#include <hip/hip_runtime.h>
#include <hip/hip_bf16.h>
#include <stdint.h>

// Problem constants (fixed by setup_inputs)
#define Bn 64
#define Sn 2048
#define Dn 768
#define An 256
#define EPSF 1e-7f
#define ROWS 32              // s-rows per chunk
#define NK (Dn / 32)         // 24 K-steps of 32

typedef __bf16 bf16x8 __attribute__((ext_vector_type(8)));
typedef float f32x4 __attribute__((ext_vector_type(4)));

// ---------------- merged prep: pack W + compact mask (one launch) ----------------
// blocks 0..95: pack W -> bf16 MFMA-B-fragment layout (4 (kk,cb) jobs/block).
//   packed[((kk*16+cb)*64+l)*8+e] = bf16( W[kk*32+(l>>4)*8+e][cb*16+(l&15)] )
// blocks 96..159: per-batch deterministic prefix-scan compaction of mask.
__global__ void prep_kernel(const float* __restrict__ W, unsigned short* __restrict__ pw,
                            const int* __restrict__ mask,
                            int* __restrict__ ridx, int* __restrict__ count) {
  const int bid = blockIdx.x;
  const int tid = threadIdx.x;
  if (bid < 96) {
    int job = bid * 4 + (tid >> 6);   // 0..383
    int l   = tid & 63;
    int kk  = job >> 4;               // 0..23
    int cb  = job & 15;               // 0..15
    int a   = cb * 16 + (l & 15);
    int k0  = kk * 32 + (l >> 4) * 8;
    bf16x8 pk;
#pragma unroll
    for (int j = 0; j < 8; ++j) pk[j] = (__bf16)W[(k0 + j) * An + a];
    *(bf16x8*)(pw + ((size_t)(job * 64 + l)) * 8) = pk;
  } else {
    __shared__ int scan[256];
    const int b = bid - 96;
    const int* mrow = mask + (size_t)b * Sn;
    int loc[8], lc = 0;
#pragma unroll
    for (int k = 0; k < 8; ++k) {
      loc[k] = mrow[tid * 8 + k];
      lc += loc[k];
    }
    scan[tid] = lc;
    __syncthreads();
    for (int off = 1; off < 256; off <<= 1) {
      int v = scan[tid];
      int add = (tid >= off) ? scan[tid - off] : 0;
      __syncthreads();
      scan[tid] = v + add;
      __syncthreads();
    }
    int o = scan[tid] - lc;           // exclusive prefix
    int* rb = ridx + (size_t)b * Sn;
#pragma unroll
    for (int k = 0; k < 8; ++k)
      if (loc[k]) rb[o++] = tid * 8 + k;
    if (tid == 255) count[b] = scan[255];
  }
}

// ---------------- main fused kernel (R15 structure, active rows only) ----------------
// grid = 4096 slots; slot (b, ci) processes active rows [ci*32, ci*32+32) of
// batch b via the compacted index list; slots past count[b] exit immediately.
// Staging: batch-issued 24 float4/thread (R11-proven) through the row gather.
// K-loop: wf[4][4] depth-4 W register rotation (R10-proven).
__launch_bounds__(256, 3)
__global__ void attn_pool_main(const float* __restrict__ x,
                               const unsigned short* __restrict__ pw,
                               const float* __restrict__ bias,
                               const float* __restrict__ u,
                               const int* __restrict__ ridx,
                               const int* __restrict__ count,
                               float* __restrict__ outpart,
                               float* __restrict__ sumpart) {
  __shared__ __align__(16) char xs[49152];   // 32 rows x 768 bf16, XOR-swizzled
  __shared__ float aitp[128];
  __shared__ float aitv[32];
  __shared__ int rows[32];

  const int tid  = threadIdx.x;
  const int lane = tid & 63;
  const int w    = tid >> 6;      // wave 0..3, cols w*64..w*64+63
  const int cid  = blockIdx.x;
  const int b    = cid >> 6;
  const int ci   = cid & 63;
  const int base = ci * ROWS;
  const int ntot = count[b];
  if (base >= ntot) return;                    // inactive slot
  const int nact = min(ROWS, ntot - base);

  if (tid < 32)
    rows[tid] = ridx[(size_t)b * Sn + base + ((tid < nact) ? tid : 0)];
  __syncthreads();

  // ---- stage x tile: 32 gathered rows x 768 fp32 -> bf16 LDS (swizzled) ----
  const float* xbb = x + (size_t)b * Sn * Dn;
  {
    float4 ldA[12], ldB[12];
#pragma unroll
    for (int j = 0; j < 12; ++j) {
      int unit = tid + j * 256;       // 0..3071 ; 8 k-elems each
      int row  = unit / 96;
      int ku   = unit % 96;
      const float4* g = (const float4*)(xbb + (size_t)rows[row] * Dn + ku * 8);
      ldA[j] = g[0];
      ldB[j] = g[1];
    }
    __builtin_amdgcn_sched_barrier(0);   // keep all 24 loads issued up-front
#pragma unroll
    for (int j = 0; j < 12; ++j) {
      int unit = tid + j * 256;
      int row  = unit / 96;
      int ku   = unit % 96;
      bf16x8 pk;
      pk[0] = (__bf16)ldA[j].x; pk[1] = (__bf16)ldA[j].y;
      pk[2] = (__bf16)ldA[j].z; pk[3] = (__bf16)ldA[j].w;
      pk[4] = (__bf16)ldB[j].x; pk[5] = (__bf16)ldB[j].y;
      pk[6] = (__bf16)ldB[j].z; pk[7] = (__bf16)ldB[j].w;
      int off = (row * 1536 + ku * 16) ^ ((row & 7) << 4);
      *(bf16x8*)(xs + off) = pk;
    }
  }

  const int arow  = lane & 15;
  const int kh16  = (lane >> 4) * 16;
  const int swz   = (arow & 7) << 4;
  const char* wlane = (const char*)pw + (size_t)(w * 4) * 1024 + (size_t)lane * 16;

  // ---- W pipeline prologue: load kk=0..3 into wf (ld regs dead now) ----
  bf16x8 wf[4][4];
#pragma unroll
  for (int s = 0; s < 4; ++s) {
    const char* wk = wlane + (size_t)s * 16384;
    wf[s][0] = *(const bf16x8*)(wk);
    wf[s][1] = *(const bf16x8*)(wk + 1024);
    wf[s][2] = *(const bf16x8*)(wk + 2048);
    wf[s][3] = *(const bf16x8*)(wk + 3072);
  }

  asm volatile("s_waitcnt lgkmcnt(0)" ::: "memory");
  __builtin_amdgcn_s_barrier();     // xs published; wf stream in flight

  f32x4 acc[2][4];
#pragma unroll
  for (int p = 0; p < 2; ++p)
#pragma unroll
    for (int q = 0; q < 4; ++q) acc[p][q] = (f32x4){0.f, 0.f, 0.f, 0.f};

  // ---- K-loop: use wf[kk&3], reload it for kk+4 (counted vmcnt waits) ----
#pragma unroll
  for (int kk = 0; kk < NK; ++kk) {
    const int s = kk & 3;
    bf16x8 a0 = *(const bf16x8*)(xs + ((arow * 1536 + kk * 64 + kh16) ^ swz));
    bf16x8 a1 = *(const bf16x8*)(xs + (((arow + 16) * 1536 + kk * 64 + kh16) ^ swz));
    bf16x8 b0 = wf[s][0], b1 = wf[s][1], b2 = wf[s][2], b3 = wf[s][3];
    if (kk + 4 < NK) {
      const char* wk = wlane + (size_t)(kk + 4) * 16384;
      wf[s][0] = *(const bf16x8*)(wk);
      wf[s][1] = *(const bf16x8*)(wk + 1024);
      wf[s][2] = *(const bf16x8*)(wk + 2048);
      wf[s][3] = *(const bf16x8*)(wk + 3072);
    }
    acc[0][0] = __builtin_amdgcn_mfma_f32_16x16x32_bf16(a0, b0, acc[0][0], 0, 0, 0);
    acc[1][0] = __builtin_amdgcn_mfma_f32_16x16x32_bf16(a1, b0, acc[1][0], 0, 0, 0);
    acc[0][1] = __builtin_amdgcn_mfma_f32_16x16x32_bf16(a0, b1, acc[0][1], 0, 0, 0);
    acc[1][1] = __builtin_amdgcn_mfma_f32_16x16x32_bf16(a1, b1, acc[1][1], 0, 0, 0);
    acc[0][2] = __builtin_amdgcn_mfma_f32_16x16x32_bf16(a0, b2, acc[0][2], 0, 0, 0);
    acc[1][2] = __builtin_amdgcn_mfma_f32_16x16x32_bf16(a1, b2, acc[1][2], 0, 0, 0);
    acc[0][3] = __builtin_amdgcn_mfma_f32_16x16x32_bf16(a0, b3, acc[0][3], 0, 0, 0);
    acc[1][3] = __builtin_amdgcn_mfma_f32_16x16x32_bf16(a1, b3, acc[1][3], 0, 0, 0);
  }

  // ---- epilogue: tanh + dot with u -> per-row partials ----
  float rowp[8];
#pragma unroll
  for (int p = 0; p < 8; ++p) rowp[p] = 0.f;
#pragma unroll
  for (int cbi = 0; cbi < 4; ++cbi) {
    int col = w * 64 + cbi * 16 + arow;
    float bia = bias[col];
    float uv  = u[col];
#pragma unroll
    for (int rb = 0; rb < 2; ++rb) {
#pragma unroll
      for (int r = 0; r < 4; ++r) {
        float v = acc[rb][cbi][r] + bia;
        v = fminf(fmaxf(v, -15.f), 15.f);
        float e2 = __expf(2.f * v);
        float th = (e2 - 1.f) * __builtin_amdgcn_rcpf(e2 + 1.f);
        rowp[rb * 4 + r] += th * uv;
      }
    }
  }
#pragma unroll
  for (int m = 1; m < 16; m <<= 1)
#pragma unroll
    for (int p = 0; p < 8; ++p) rowp[p] += __shfl_xor(rowp[p], m, 64);

  if (arow == 0) {
    int rbase = (lane >> 4) * 4;
#pragma unroll
    for (int rb = 0; rb < 2; ++rb)
#pragma unroll
      for (int r = 0; r < 4; ++r)
        aitp[w * 32 + rb * 16 + rbase + r] = rowp[rb * 4 + r];
  }
  __syncthreads();

  // ---- ait = exp(sum) for active rows, 0 for pad ; chunk sum ----
  if (tid < 32) {
    float s = aitp[tid] + aitp[32 + tid] + aitp[64 + tid] + aitp[96 + tid];
    float av = (tid < nact) ? __expf(s) : 0.f;
    aitv[tid] = av;
    float t = av;
#pragma unroll
    for (int m = 1; m < 32; m <<= 1) t += __shfl_xor(t, m, 64);
    if (tid == 0) sumpart[cid] = t;
  }
  __syncthreads();

  // ---- pooling: 192 threads, 2 row-groups of 16 rows ----
  float pac[8];
#pragma unroll
  for (int e = 0; e < 8; ++e) pac[e] = 0.f;
  int rg = tid / 96;              // 0..1 for tid<192
  int du = tid % 96;              // 8-d unit
  if (tid < 192) {
#pragma unroll
    for (int rr = 0; rr < 16; ++rr) {
      int row = rg * 16 + rr;
      int off = (row * 1536 + du * 16) ^ ((row & 7) << 4);
      bf16x8 xv = *(const bf16x8*)(xs + off);
      float a = aitv[row];
#pragma unroll
      for (int e = 0; e < 8; ++e) pac[e] += a * (float)xv[e];
    }
  }
  __syncthreads();   // all xs reads done -> safe to overlay outred onto xs

  float* outred = (float*)xs;     // [2][768] overlay
  if (tid < 192) {
#pragma unroll
    for (int e = 0; e < 8; ++e) outred[rg * 768 + du * 8 + e] = pac[e];
  }
  __syncthreads();

  {
    float* op = outpart + (size_t)cid * Dn;
#pragma unroll
    for (int j = 0; j < 3; ++j) {
      int d = tid + j * 256;
      op[d] = outred[d] + outred[768 + d];
    }
  }
}

// ---------------- finalize: out[b,d] = sum over written chunks / (sum + eps) ----
// grid = 64 b x 3 slabs of 256 d; reads only the ceil(count/32) written slots.
__global__ void finalize_kernel(const float* __restrict__ outpart,
                                const float* __restrict__ sumpart,
                                const int* __restrict__ count,
                                float* __restrict__ out) {
  __shared__ float sh;
  int b = blockIdx.x / 3, slab = blockIdx.x % 3;
  int tid = threadIdx.x;
  const int nch = (count[b] + ROWS - 1) / ROWS;   // written chunk slots
  if (tid < 64) {
    float v = (tid < nch) ? sumpart[b * 64 + tid] : 0.f;
#pragma unroll
    for (int m = 1; m < 64; m <<= 1) v += __shfl_xor(v, m, 64);
    if (tid == 0) sh = v + EPSF;
  }
  __syncthreads();
  float inv = 1.0f / sh;
  int d = slab * 256 + tid;
  const float* p = outpart + (size_t)b * 64 * Dn + d;
  float s = 0.f;
  for (int c = 0; c < nch; ++c) s += p[(size_t)c * Dn];
  out[b * Dn + d] = s * inv;
}

extern "C" void kernel_launch(void* const* d_in, const int* in_sizes, int n_in,
                              void* d_out, int out_size, void* d_ws, size_t ws_size,
                              hipStream_t stream) {
  const float* x    = (const float*)d_in[0];
  const float* W    = (const float*)d_in[1];
  const float* bias = (const float*)d_in[2];
  const float* u    = (const float*)d_in[3];
  const int*   mask = (const int*)d_in[4];
  float* out = (float*)d_out;

  unsigned short* pw = (unsigned short*)d_ws;                       // 384 KB
  float* outpart = (float*)((char*)d_ws + 393216);                  // 12.58 MB
  float* sumpart = (float*)((char*)d_ws + 393216 + 12582912);       // 16 KB
  int*   ridx    = (int*)((char*)d_ws + 393216 + 12582912 + 16384); // 512 KB
  int*   count   = (int*)((char*)d_ws + 393216 + 12582912 + 16384 + 524288); // 256 B

  hipLaunchKernelGGL(prep_kernel, dim3(160), dim3(256), 0, stream,
                     W, pw, mask, ridx, count);
  hipLaunchKernelGGL(attn_pool_main, dim3(Bn * 64), dim3(256), 0, stream,
                     x, pw, bias, u, ridx, count, outpart, sumpart);
  hipLaunchKernelGGL(finalize_kernel, dim3(Bn * 3), dim3(256), 0, stream,
                     outpart, sumpart, count, out);
}